// Round 5
// baseline (2008.806 us; speedup 1.0000x reference)
//
#include <hip/hip_runtime.h>
#include <hip/hip_bf16.h>

#define NQ 10000
#define BS 6
#define NV 30825   // 23200 + 5800 + 1450 + 375

// vproj layout per batch (64B units = one head-row of 32ch bf16):
//   level l: unit = ubase[l] + (y*8 + h)*W + x   (x-adjacent => contiguous)
//   ubase: 0, 185600, 232000, 243600 ; per-batch 246600 units (15,782,400 B)

typedef __attribute__((ext_vector_type(8))) short bf16x8;
typedef __attribute__((ext_vector_type(8))) unsigned short u16x8;
typedef __attribute__((ext_vector_type(4))) float f32x4;
typedef __attribute__((ext_vector_type(2))) float f32x2;

__device__ __forceinline__ void gload_lds16(const void* g, void* l) {
  __builtin_amdgcn_global_load_lds(
      (const __attribute__((address_space(1))) unsigned int*)g,
      (__attribute__((address_space(3))) unsigned int*)l, 16, 0, 0);
}

__device__ __forceinline__ unsigned short bf_bits(float f) {
  __hip_bfloat16 h = __float2bfloat16(f);
  return *(unsigned short*)&h;
}
__device__ __forceinline__ float bfu(unsigned short u) {
  return __uint_as_float((unsigned)u << 16);
}

// ---------------------------------------------------------------------------
// Pack + transpose weights to bf16.
// ---------------------------------------------------------------------------
__global__ __launch_bounds__(256) void prep_weights_kernel(
    const float* __restrict__ w_val, const float* __restrict__ w_off,
    const float* __restrict__ w_attn, const float* __restrict__ b_off,
    const float* __restrict__ b_attn, unsigned short* __restrict__ wvalT,
    unsigned short* __restrict__ wpackT, float* __restrict__ bpack) {
  int i = blockIdx.x * 256 + threadIdx.x;
  if (i < 65536) {
    int n = i >> 8, k = i & 255;
    wvalT[i] = bf_bits(w_val[k * 256 + n]);
  } else if (i < 65536 + 196608) {
    int j = i - 65536;
    int n = j >> 8, k = j & 255;
    float v = (n < 512) ? w_off[k * 512 + n] : w_attn[k * 256 + (n - 512)];
    wpackT[j] = bf_bits(v);
  } else if (i < 65536 + 196608 + 768) {
    int j = i - 262144;
    bpack[j] = (j < 512) ? b_off[j] : b_attn[j - 512];
  }
}

// ---------------------------------------------------------------------------
// MFMA GEMM with fused A conversion (unchanged from round 3).
// ---------------------------------------------------------------------------
template <bool SCATTER>
__global__ __launch_bounds__(256) void gemm_mfma_kernel(
    const float* __restrict__ A, const unsigned short* __restrict__ WT,
    const float* __restrict__ bias, unsigned short* __restrict__ C, int M, int N) {
  __shared__ short As[128 * 64];
  __shared__ short Bs[128 * 64];
  const int tid = threadIdx.x;
  const int wv = tid >> 6;
  const int lane = tid & 63;
  const int wr = wv >> 1, wc = wv & 1;
  const int m0 = blockIdx.x * 128;
  const int n0 = blockIdx.y * 128;

  f32x4 acc[4][4] = {};

  for (int kt = 0; kt < 4; ++kt) {
#pragma unroll
    for (int j = 0; j < 4; ++j) {
      int u = j * 256 + tid;
      int row = u >> 3;
      int kbyte = (u & 7) * 16;
      int ldsoff = (j * 256 + wv * 64) * 16;
      gload_lds16((const char*)WT + (size_t)(n0 + row) * 512 + kt * 128 + kbyte,
                  (char*)Bs + ldsoff);
    }
#pragma unroll
    for (int j = 0; j < 4; ++j) {
      int u = j * 256 + tid;
      int row = u >> 3, oct = u & 7;
      int gr = m0 + row; if (gr >= M) gr = M - 1;
      const float4* ap = (const float4*)(A + (size_t)gr * 256 + kt * 64 + oct * 8);
      float4 a0 = ap[0], a1 = ap[1];
      u16x8 pk = { bf_bits(a0.x), bf_bits(a0.y), bf_bits(a0.z), bf_bits(a0.w),
                   bf_bits(a1.x), bf_bits(a1.y), bf_bits(a1.z), bf_bits(a1.w) };
      *(u16x8*)&As[row * 64 + oct * 8] = pk;
    }
    __syncthreads();
#pragma unroll
    for (int kk = 0; kk < 2; ++kk) {
      bf16x8 af[4], bfr[4];
#pragma unroll
      for (int mi = 0; mi < 4; ++mi) {
        int off = (wr * 64 + mi * 16 + (lane & 15)) * 64 + kk * 32 + (lane >> 4) * 8;
        af[mi] = *(const bf16x8*)&As[off];
      }
#pragma unroll
      for (int ni = 0; ni < 4; ++ni) {
        int off = (wc * 64 + ni * 16 + (lane & 15)) * 64 + kk * 32 + (lane >> 4) * 8;
        bfr[ni] = *(const bf16x8*)&Bs[off];
      }
#pragma unroll
      for (int mi = 0; mi < 4; ++mi)
#pragma unroll
        for (int ni = 0; ni < 4; ++ni)
          acc[mi][ni] = __builtin_amdgcn_mfma_f32_16x16x32_bf16(
              af[mi], bfr[ni], acc[mi][ni], 0, 0, 0);
    }
    __syncthreads();
  }

  const int colb = n0 + wc * 64 + (lane & 15);
  float bvn[4];
#pragma unroll
  for (int ni = 0; ni < 4; ++ni) bvn[ni] = bias[colb + ni * 16];
#pragma unroll
  for (int mi = 0; mi < 4; ++mi) {
#pragma unroll
    for (int r = 0; r < 4; ++r) {
      int row = m0 + wr * 64 + mi * 16 + (lane >> 4) * 4 + r;
      if (row >= M) continue;
      if (!SCATTER) {
#pragma unroll
        for (int ni = 0; ni < 4; ++ni)
          C[(size_t)row * N + colb + ni * 16] = bf_bits(acc[mi][ni][r] + bvn[ni]);
      } else {
        int b = row / NV;
        int pix = row - b * NV;
        int ubase, Wl, y, x;
        if (pix < 23200)      { int pl = pix;         y = pl / 200; x = pl - y * 200; ubase = 0;      Wl = 200; }
        else if (pix < 29000) { int pl = pix - 23200; y = pl / 100; x = pl - y * 100; ubase = 185600; Wl = 100; }
        else if (pix < 30450) { int pl = pix - 29000; y = pl / 50;  x = pl - y * 50;  ubase = 232000; Wl = 50;  }
        else                  { int pl = pix - 30450; y = pl / 25;  x = pl - y * 25;  ubase = 243600; Wl = 25;  }
        size_t bu = (size_t)b * 246600 + ubase + (size_t)(y * 8) * Wl + x;
#pragma unroll
        for (int ni = 0; ni < 4; ++ni) {
          int col = colb + ni * 16;
          int h = col >> 5, ch = col & 31;
          C[(bu + (size_t)h * Wl) * 32 + ch] = bf_bits(acc[mi][ni][r] + bvn[ni]);
        }
      }
    }
  }
}

// ---------------------------------------------------------------------------
// Spatial counting sort of 240000 (b,q,z) items by (batch, 16x16 Morton cell).
// ---------------------------------------------------------------------------
__device__ __forceinline__ int item_key(const float* ref, int i) {
  int b = i / 40000;
  int rem = i - b * 40000;
  int q = rem >> 2, z = rem & 3;
  float2 rz = *(const float2*)(ref + (size_t)(b * NQ + q) * 8 + z * 2);
  int xq = min(max((int)(rz.x * 16.f), 0), 15);
  int yq = min(max((int)(rz.y * 16.f), 0), 15);
  int m = 0;
#pragma unroll
  for (int j = 0; j < 4; ++j)
    m |= (((xq >> j) & 1) << (2 * j)) | (((yq >> j) & 1) << (2 * j + 1));
  return b * 256 + m;
}

__global__ __launch_bounds__(256) void cell_hist_kernel(
    const float* __restrict__ ref, unsigned* __restrict__ hist) {
  int i = blockIdx.x * 256 + threadIdx.x;
  if (i >= BS * NQ * 4) return;
  atomicAdd(&hist[item_key(ref, i)], 1u);
}

__global__ __launch_bounds__(256) void scan_kernel(unsigned* __restrict__ hist) {
  __shared__ unsigned sdata[256];
  int tid = threadIdx.x;
  unsigned v[6], sum = 0;
#pragma unroll
  for (int j = 0; j < 6; ++j) { v[j] = hist[tid * 6 + j]; sum += v[j]; }
  sdata[tid] = sum;
  __syncthreads();
  for (int d = 1; d < 256; d <<= 1) {
    unsigned t = (tid >= d) ? sdata[tid - d] : 0u;
    __syncthreads();
    sdata[tid] += t;
    __syncthreads();
  }
  unsigned excl = (tid > 0) ? sdata[tid - 1] : 0u;
#pragma unroll
  for (int j = 0; j < 6; ++j) { hist[tid * 6 + j] = excl; excl += v[j]; }
}

__global__ __launch_bounds__(256) void cell_scatter_kernel(
    const float* __restrict__ ref, unsigned* __restrict__ cursor,
    unsigned* __restrict__ perm) {
  int i = blockIdx.x * 256 + threadIdx.x;
  if (i >= BS * NQ * 4) return;
  unsigned pos = atomicAdd(&cursor[item_key(ref, i)], 1u);
  perm[pos] = (unsigned)i;
}

// ---------------------------------------------------------------------------
// Sampling kernel: 4 waves/block, each wave = one sorted (b,q,z) item.
// Lane (h = lane>>3, sub = lane&7 = l*2+p2): fused softmax (zero cross-lane
// weight lookup: lane's own slot z holds its sample's logit), bilinear setup
// -> LDS; then 8-lane-cooperative 128B pair gathers; f32 atomicAdd to out.
// ---------------------------------------------------------------------------
__global__ __launch_bounds__(256) void msda_sample_kernel(
    const __hip_bfloat16* __restrict__ vproj,
    const __hip_bfloat16* __restrict__ C2,   // [BS*NQ,768]: 512 off | 256 attn
    const float* __restrict__ ref,
    const unsigned* __restrict__ perm,
    float* __restrict__ out) {
  const int tid = threadIdx.x;
  const int wv = tid >> 6, lane = tid & 63;
  const int sblk = (blockIdx.x & 7) * 7500 + (blockIdx.x >> 3);  // XCD swizzle
  const unsigned item = perm[sblk * 4 + wv];
  const int b = item / 40000;
  const int rem = item - b * 40000;
  const int q = rem >> 2, z = rem & 3;
  const int bq = b * NQ + q;

  __shared__ int    s_pidx[4][8][17];
  __shared__ float2 s_w2[4][8][17];

  const int h = lane >> 3, sub = lane & 7;
  {
    // --- fused softmax: lane loads 4 logits [h*32 + sub*4 .. +4] ---
    ushort4 lg = *(const ushort4*)((const unsigned short*)C2 +
                                   (size_t)bq * 768 + 512 + lane * 4);
    float l0 = bfu(lg.x), l1 = bfu(lg.y), l2 = bfu(lg.z), l3 = bfu(lg.w);
    float mx = fmaxf(fmaxf(l0, l1), fmaxf(l2, l3));
    mx = fmaxf(mx, __shfl_xor(mx, 1));
    mx = fmaxf(mx, __shfl_xor(mx, 2));
    mx = fmaxf(mx, __shfl_xor(mx, 4));
    float e0 = __expf(l0 - mx), e1 = __expf(l1 - mx),
          e2 = __expf(l2 - mx), e3 = __expf(l3 - mx);
    float sm = e0 + e1 + e2 + e3;
    sm += __shfl_xor(sm, 1);
    sm += __shfl_xor(sm, 2);
    sm += __shfl_xor(sm, 4);
    float ez = (z == 0) ? e0 : (z == 1) ? e1 : (z == 2) ? e2 : e3;
    float aw = ez / sm;

    // --- bilinear setup for sample (h, l, p = z + 4*p2) ---
    const int l = sub >> 1, p2 = sub & 1, p = z + 4 * p2;
    __hip_bfloat162 ob = *(const __hip_bfloat162*)((const unsigned short*)C2 +
        (size_t)bq * 768 + (((h * 4 + l) * 8 + p) << 1));
    float ox = __bfloat162float(ob.x), oy = __bfloat162float(ob.y);
    float2 rz = *(const float2*)(ref + (size_t)bq * 8 + z * 2);

    const int W = (l == 0) ? 200 : (l == 1) ? 100 : (l == 2) ? 50 : 25;
    const int H = (l == 0) ? 116 : (l == 1) ? 58 : (l == 2) ? 29 : 15;
    const int ub = (l == 0) ? 0 : (l == 1) ? 185600 : (l == 2) ? 232000 : 243600;

    float x = rz.x * (float)W + ox - 0.5f;
    float y = rz.y * (float)H + oy - 0.5f;
    float x0f = floorf(x), y0f = floorf(y);
    float lx = x - x0f, ly = y - y0f;
    int x0 = (int)x0f, y0 = (int)y0f;
    int x1 = x0 + 1, y1 = y0 + 1;

    float wx0 = 1.f - lx, wx1 = lx;
    if (!((x0 >= 0) & (x0 < W))) wx0 = 0.f;
    if (!((x1 >= 0) & (x1 < W))) wx1 = 0.f;
    float wy0 = (1.f - ly) * aw, wy1 = ly * aw;
    if (!((y0 >= 0) & (y0 < H))) wy0 = 0.f;
    if (!((y1 >= 0) & (y1 < H))) wy1 = 0.f;

    int px  = min(max(x0, 0), W - 2);
    int x0c = min(max(x0, 0), W - 1);
    int x1c = min(max(x1, 0), W - 1);
    float wA = (x0c == px     ? wx0 : 0.f) + (x1c == px     ? wx1 : 0.f);
    float wB = (x0c == px + 1 ? wx0 : 0.f) + (x1c == px + 1 ? wx1 : 0.f);
    int y0c = min(max(y0, 0), H - 1);
    int y1c = min(max(y1, 0), H - 1);

    s_pidx[wv][h][sub * 2 + 0] = ub + (y0c * 8 + h) * W + px;
    s_w2[wv][h][sub * 2 + 0]   = make_float2(wy0 * wA, wy0 * wB);
    s_pidx[wv][h][sub * 2 + 1] = ub + (y1c * 8 + h) * W + px;
    s_w2[wv][h][sub * 2 + 1]   = make_float2(wy1 * wA, wy1 * wB);
  }
  __syncthreads();

  // --- phase 2: 8-lane cooperative 128B pair gathers ---
  const int colhalf = sub >> 2, e = sub & 3;
  const char* vbb = (const char*)vproj + (size_t)b * 15782400 + sub * 16;

  f32x2 acc0 = {0.f, 0.f}, acc1 = {0.f, 0.f}, acc2 = {0.f, 0.f}, acc3 = {0.f, 0.f};
#pragma unroll
  for (int t = 0; t < 16; ++t) {
    int pidx = s_pidx[wv][h][t];
    float2 w2 = s_w2[wv][h][t];
    float w = colhalf ? w2.y : w2.x;
    uint4 v = *(const uint4*)(vbb + ((size_t)(unsigned)pidx << 6));
    f32x2 wvv = {w, w};
    f32x2 p0 = {__uint_as_float(v.x << 16), __uint_as_float(v.x & 0xffff0000u)};
    f32x2 p1 = {__uint_as_float(v.y << 16), __uint_as_float(v.y & 0xffff0000u)};
    f32x2 p2 = {__uint_as_float(v.z << 16), __uint_as_float(v.z & 0xffff0000u)};
    f32x2 p3 = {__uint_as_float(v.w << 16), __uint_as_float(v.w & 0xffff0000u)};
    acc0 += wvv * p0;
    acc1 += wvv * p1;
    acc2 += wvv * p2;
    acc3 += wvv * p3;
  }

  acc0.x += __shfl_xor(acc0.x, 4);  acc0.y += __shfl_xor(acc0.y, 4);
  acc1.x += __shfl_xor(acc1.x, 4);  acc1.y += __shfl_xor(acc1.y, 4);
  acc2.x += __shfl_xor(acc2.x, 4);  acc2.y += __shfl_xor(acc2.y, 4);
  acc3.x += __shfl_xor(acc3.x, 4);  acc3.y += __shfl_xor(acc3.y, 4);

  if (!colhalf) {
    float* op = out + (size_t)bq * 256 + h * 32 + e * 8;
    atomicAdd(op + 0, acc0.x);
    atomicAdd(op + 1, acc0.y);
    atomicAdd(op + 2, acc1.x);
    atomicAdd(op + 3, acc1.y);
    atomicAdd(op + 4, acc2.x);
    atomicAdd(op + 5, acc2.y);
    atomicAdd(op + 6, acc3.x);
    atomicAdd(op + 7, acc3.y);
  }
}

extern "C" void kernel_launch(void* const* d_in, const int* in_sizes, int n_in,
                              void* d_out, int out_size, void* d_ws, size_t ws_size,
                              hipStream_t stream) {
  const float* query  = (const float*)d_in[0];
  const float* value  = (const float*)d_in[1];
  const float* refp   = (const float*)d_in[2];
  const float* w_off  = (const float*)d_in[3];
  const float* b_off  = (const float*)d_in[4];
  const float* w_attn = (const float*)d_in[5];
  const float* b_attn = (const float*)d_in[6];
  const float* w_val  = (const float*)d_in[7];
  const float* b_val  = (const float*)d_in[8];
  float* out = (float*)d_out;

  char* ws = (char*)d_ws;
  // layout (bytes):
  //   vproj  bf16 level-blocked  @ 0           (94,694,400)
  //   C2     bf16 [60000*768]    @ 94,694,400  (92,160,000)
  //   wvalT  bf16 [256*256]      @ 186,854,400 (131,072)
  //   wpackT bf16 [768*256]      @ 186,985,472 (393,216)
  //   bpack  f32  [768]          @ 187,378,688 (3,072)
  //   perm   u32  [240000]       @ 187,381,760 (960,000)
  //   hist   u32  [1536]         @ 188,341,760 (6,144)   -> end 188,347,904
  unsigned short* vproj  = (unsigned short*)(ws);
  unsigned short* C2     = (unsigned short*)(ws + 94694400);
  unsigned short* wvalT  = (unsigned short*)(ws + 186854400);
  unsigned short* wpackT = (unsigned short*)(ws + 186985472);
  float*          bpack  = (float*)        (ws + 187378688);
  unsigned*       perm   = (unsigned*)     (ws + 187381760);
  unsigned*       hist   = (unsigned*)     (ws + 188341760);

  const int Mv = BS * NV;  // 184950
  const int Mq = BS * NQ;  // 60000
  const int NITEMS = BS * NQ * 4;  // 240000

  hipMemsetAsync(hist, 0, 1536 * 4, stream);
  hipMemsetAsync(out, 0, (size_t)out_size * 4, stream);

  cell_hist_kernel<<<(NITEMS + 255) / 256, 256, 0, stream>>>(refp, hist);
  scan_kernel<<<1, 256, 0, stream>>>(hist);
  cell_scatter_kernel<<<(NITEMS + 255) / 256, 256, 0, stream>>>(refp, hist, perm);

  prep_weights_kernel<<<1032, 256, 0, stream>>>(w_val, w_off, w_attn, b_off, b_attn,
                                                wvalT, wpackT, bpack);
  gemm_mfma_kernel<true><<<dim3((Mv + 127) / 128, 2), 256, 0, stream>>>(
      value, wvalT, b_val, vproj, Mv, 256);
  gemm_mfma_kernel<false><<<dim3((Mq + 127) / 128, 6), 256, 0, stream>>>(
      query, wpackT, bpack, C2, Mq, 768);

  msda_sample_kernel<<<60000, 256, 0, stream>>>(
      (const __hip_bfloat16*)vproj, (const __hip_bfloat16*)C2, refp, perm, out);
}

// Round 6
// 508.176 us; speedup vs baseline: 3.9530x; 3.9530x over previous
//
#include <hip/hip_runtime.h>
#include <hip/hip_bf16.h>
#include <hip/hip_fp16.h>

#define NQ 10000
#define BS 6
#define NV 30825   // 23200 + 5800 + 1450 + 375

// vproj layout per batch (64B units = one head-row of 32ch bf16):
//   level l: unit = ubase[l] + (y*8 + h)*W + x   (x-adjacent => contiguous)
//   ubase: 0, 185600, 232000, 243600 ; per-batch 246600 units (15,782,400 B)

typedef __attribute__((ext_vector_type(8))) short bf16x8;
typedef __attribute__((ext_vector_type(8))) unsigned short u16x8;
typedef __attribute__((ext_vector_type(4))) float f32x4;
typedef __attribute__((ext_vector_type(2))) float f32x2;

__device__ __forceinline__ void gload_lds16(const void* g, void* l) {
  __builtin_amdgcn_global_load_lds(
      (const __attribute__((address_space(1))) unsigned int*)g,
      (__attribute__((address_space(3))) unsigned int*)l, 16, 0, 0);
}

__device__ __forceinline__ unsigned short bf_bits(float f) {
  __hip_bfloat16 h = __float2bfloat16(f);
  return *(unsigned short*)&h;
}
__device__ __forceinline__ float bfu(unsigned short u) {
  return __uint_as_float((unsigned)u << 16);
}

// ---------------------------------------------------------------------------
// Pack + transpose weights to bf16.
// ---------------------------------------------------------------------------
__global__ __launch_bounds__(256) void prep_weights_kernel(
    const float* __restrict__ w_val, const float* __restrict__ w_off,
    const float* __restrict__ w_attn, const float* __restrict__ b_off,
    const float* __restrict__ b_attn, unsigned short* __restrict__ wvalT,
    unsigned short* __restrict__ wpackT, float* __restrict__ bpack) {
  int i = blockIdx.x * 256 + threadIdx.x;
  if (i < 65536) {
    int n = i >> 8, k = i & 255;
    wvalT[i] = bf_bits(w_val[k * 256 + n]);
  } else if (i < 65536 + 196608) {
    int j = i - 65536;
    int n = j >> 8, k = j & 255;
    float v = (n < 512) ? w_off[k * 512 + n] : w_attn[k * 256 + (n - 512)];
    wpackT[j] = bf_bits(v);
  } else if (i < 65536 + 196608 + 768) {
    int j = i - 262144;
    bpack[j] = (j < 512) ? b_off[j] : b_attn[j - 512];
  }
}

// ---------------------------------------------------------------------------
// MFMA GEMM with fused A conversion (unchanged).
// ---------------------------------------------------------------------------
template <bool SCATTER>
__global__ __launch_bounds__(256) void gemm_mfma_kernel(
    const float* __restrict__ A, const unsigned short* __restrict__ WT,
    const float* __restrict__ bias, unsigned short* __restrict__ C, int M, int N) {
  __shared__ short As[128 * 64];
  __shared__ short Bs[128 * 64];
  const int tid = threadIdx.x;
  const int wv = tid >> 6;
  const int lane = tid & 63;
  const int wr = wv >> 1, wc = wv & 1;
  const int m0 = blockIdx.x * 128;
  const int n0 = blockIdx.y * 128;

  f32x4 acc[4][4] = {};

  for (int kt = 0; kt < 4; ++kt) {
#pragma unroll
    for (int j = 0; j < 4; ++j) {
      int u = j * 256 + tid;
      int row = u >> 3;
      int kbyte = (u & 7) * 16;
      int ldsoff = (j * 256 + wv * 64) * 16;
      gload_lds16((const char*)WT + (size_t)(n0 + row) * 512 + kt * 128 + kbyte,
                  (char*)Bs + ldsoff);
    }
#pragma unroll
    for (int j = 0; j < 4; ++j) {
      int u = j * 256 + tid;
      int row = u >> 3, oct = u & 7;
      int gr = m0 + row; if (gr >= M) gr = M - 1;
      const float4* ap = (const float4*)(A + (size_t)gr * 256 + kt * 64 + oct * 8);
      float4 a0 = ap[0], a1 = ap[1];
      u16x8 pk = { bf_bits(a0.x), bf_bits(a0.y), bf_bits(a0.z), bf_bits(a0.w),
                   bf_bits(a1.x), bf_bits(a1.y), bf_bits(a1.z), bf_bits(a1.w) };
      *(u16x8*)&As[row * 64 + oct * 8] = pk;
    }
    __syncthreads();
#pragma unroll
    for (int kk = 0; kk < 2; ++kk) {
      bf16x8 af[4], bfr[4];
#pragma unroll
      for (int mi = 0; mi < 4; ++mi) {
        int off = (wr * 64 + mi * 16 + (lane & 15)) * 64 + kk * 32 + (lane >> 4) * 8;
        af[mi] = *(const bf16x8*)&As[off];
      }
#pragma unroll
      for (int ni = 0; ni < 4; ++ni) {
        int off = (wc * 64 + ni * 16 + (lane & 15)) * 64 + kk * 32 + (lane >> 4) * 8;
        bfr[ni] = *(const bf16x8*)&Bs[off];
      }
#pragma unroll
      for (int mi = 0; mi < 4; ++mi)
#pragma unroll
        for (int ni = 0; ni < 4; ++ni)
          acc[mi][ni] = __builtin_amdgcn_mfma_f32_16x16x32_bf16(
              af[mi], bfr[ni], acc[mi][ni], 0, 0, 0);
    }
    __syncthreads();
  }

  const int colb = n0 + wc * 64 + (lane & 15);
  float bvn[4];
#pragma unroll
  for (int ni = 0; ni < 4; ++ni) bvn[ni] = bias[colb + ni * 16];
#pragma unroll
  for (int mi = 0; mi < 4; ++mi) {
#pragma unroll
    for (int r = 0; r < 4; ++r) {
      int row = m0 + wr * 64 + mi * 16 + (lane >> 4) * 4 + r;
      if (row >= M) continue;
      if (!SCATTER) {
#pragma unroll
        for (int ni = 0; ni < 4; ++ni)
          C[(size_t)row * N + colb + ni * 16] = bf_bits(acc[mi][ni][r] + bvn[ni]);
      } else {
        int b = row / NV;
        int pix = row - b * NV;
        int ubase, Wl, y, x;
        if (pix < 23200)      { int pl = pix;         y = pl / 200; x = pl - y * 200; ubase = 0;      Wl = 200; }
        else if (pix < 29000) { int pl = pix - 23200; y = pl / 100; x = pl - y * 100; ubase = 185600; Wl = 100; }
        else if (pix < 30450) { int pl = pix - 29000; y = pl / 50;  x = pl - y * 50;  ubase = 232000; Wl = 50;  }
        else                  { int pl = pix - 30450; y = pl / 25;  x = pl - y * 25;  ubase = 243600; Wl = 25;  }
        size_t bu = (size_t)b * 246600 + ubase + (size_t)(y * 8) * Wl + x;
#pragma unroll
        for (int ni = 0; ni < 4; ++ni) {
          int col = colb + ni * 16;
          int h = col >> 5, ch = col & 31;
          C[(bu + (size_t)h * Wl) * 32 + ch] = bf_bits(acc[mi][ni][r] + bvn[ni]);
        }
      }
    }
  }
}

// ---------------------------------------------------------------------------
// Spatial counting sort of 240000 (b,q,z) items by (batch, 16x16 Morton cell).
// ---------------------------------------------------------------------------
__device__ __forceinline__ int item_key(const float* ref, int i) {
  int b = i / 40000;
  int rem = i - b * 40000;
  int q = rem >> 2, z = rem & 3;
  float2 rz = *(const float2*)(ref + (size_t)(b * NQ + q) * 8 + z * 2);
  int xq = min(max((int)(rz.x * 16.f), 0), 15);
  int yq = min(max((int)(rz.y * 16.f), 0), 15);
  int m = 0;
#pragma unroll
  for (int j = 0; j < 4; ++j)
    m |= (((xq >> j) & 1) << (2 * j)) | (((yq >> j) & 1) << (2 * j + 1));
  return b * 256 + m;
}

__global__ __launch_bounds__(256) void cell_hist_kernel(
    const float* __restrict__ ref, unsigned* __restrict__ hist) {
  int i = blockIdx.x * 256 + threadIdx.x;
  if (i >= BS * NQ * 4) return;
  atomicAdd(&hist[item_key(ref, i)], 1u);
}

__global__ __launch_bounds__(256) void scan_kernel(unsigned* __restrict__ hist) {
  __shared__ unsigned sdata[256];
  int tid = threadIdx.x;
  unsigned v[6], sum = 0;
#pragma unroll
  for (int j = 0; j < 6; ++j) { v[j] = hist[tid * 6 + j]; sum += v[j]; }
  sdata[tid] = sum;
  __syncthreads();
  for (int d = 1; d < 256; d <<= 1) {
    unsigned t = (tid >= d) ? sdata[tid - d] : 0u;
    __syncthreads();
    sdata[tid] += t;
    __syncthreads();
  }
  unsigned excl = (tid > 0) ? sdata[tid - 1] : 0u;
#pragma unroll
  for (int j = 0; j < 6; ++j) { hist[tid * 6 + j] = excl; excl += v[j]; }
}

__global__ __launch_bounds__(256) void cell_scatter_kernel(
    const float* __restrict__ ref, unsigned* __restrict__ cursor,
    unsigned* __restrict__ perm) {
  int i = blockIdx.x * 256 + threadIdx.x;
  if (i >= BS * NQ * 4) return;
  unsigned pos = atomicAdd(&cursor[item_key(ref, i)], 1u);
  perm[pos] = (unsigned)i;
}

// ---------------------------------------------------------------------------
// Stage A: 4 waves/block, each wave = one sorted (b,q,z) item.
// Fused softmax + bilinear setup -> LDS; 8-lane cooperative 128B pair
// gathers; per-item 256-channel partial written NON-ATOMICALLY as f16 to
// partial[item] (512B contiguous per wave).
// ---------------------------------------------------------------------------
__global__ __launch_bounds__(256) void msda_sample_kernel(
    const __hip_bfloat16* __restrict__ vproj,
    const __hip_bfloat16* __restrict__ C2,   // [BS*NQ,768]: 512 off | 256 attn
    const float* __restrict__ ref,
    const unsigned* __restrict__ perm,
    __half* __restrict__ partial) {          // [BS*NQ*4][256] f16
  const int tid = threadIdx.x;
  const int wv = tid >> 6, lane = tid & 63;
  const int sblk = (blockIdx.x & 7) * 7500 + (blockIdx.x >> 3);  // XCD swizzle
  const unsigned item = perm[sblk * 4 + wv];
  const int b = item / 40000;
  const int rem = item - b * 40000;
  const int q = rem >> 2, z = rem & 3;
  const int bq = b * NQ + q;

  __shared__ int    s_pidx[4][8][17];
  __shared__ float2 s_w2[4][8][17];

  const int h = lane >> 3, sub = lane & 7;
  {
    // --- fused softmax: lane loads 4 logits [h*32 + sub*4 .. +4] ---
    ushort4 lg = *(const ushort4*)((const unsigned short*)C2 +
                                   (size_t)bq * 768 + 512 + lane * 4);
    float l0 = bfu(lg.x), l1 = bfu(lg.y), l2 = bfu(lg.z), l3 = bfu(lg.w);
    float mx = fmaxf(fmaxf(l0, l1), fmaxf(l2, l3));
    mx = fmaxf(mx, __shfl_xor(mx, 1));
    mx = fmaxf(mx, __shfl_xor(mx, 2));
    mx = fmaxf(mx, __shfl_xor(mx, 4));
    float e0 = __expf(l0 - mx), e1 = __expf(l1 - mx),
          e2 = __expf(l2 - mx), e3 = __expf(l3 - mx);
    float sm = e0 + e1 + e2 + e3;
    sm += __shfl_xor(sm, 1);
    sm += __shfl_xor(sm, 2);
    sm += __shfl_xor(sm, 4);
    float ez = (z == 0) ? e0 : (z == 1) ? e1 : (z == 2) ? e2 : e3;
    float aw = ez / sm;

    // --- bilinear setup for sample (h, l, p = z + 4*p2) ---
    const int l = sub >> 1, p2 = sub & 1, p = z + 4 * p2;
    __hip_bfloat162 ob = *(const __hip_bfloat162*)((const unsigned short*)C2 +
        (size_t)bq * 768 + (((h * 4 + l) * 8 + p) << 1));
    float ox = __bfloat162float(ob.x), oy = __bfloat162float(ob.y);
    float2 rz = *(const float2*)(ref + (size_t)bq * 8 + z * 2);

    const int W = (l == 0) ? 200 : (l == 1) ? 100 : (l == 2) ? 50 : 25;
    const int H = (l == 0) ? 116 : (l == 1) ? 58 : (l == 2) ? 29 : 15;
    const int ub = (l == 0) ? 0 : (l == 1) ? 185600 : (l == 2) ? 232000 : 243600;

    float x = rz.x * (float)W + ox - 0.5f;
    float y = rz.y * (float)H + oy - 0.5f;
    float x0f = floorf(x), y0f = floorf(y);
    float lx = x - x0f, ly = y - y0f;
    int x0 = (int)x0f, y0 = (int)y0f;
    int x1 = x0 + 1, y1 = y0 + 1;

    float wx0 = 1.f - lx, wx1 = lx;
    if (!((x0 >= 0) & (x0 < W))) wx0 = 0.f;
    if (!((x1 >= 0) & (x1 < W))) wx1 = 0.f;
    float wy0 = (1.f - ly) * aw, wy1 = ly * aw;
    if (!((y0 >= 0) & (y0 < H))) wy0 = 0.f;
    if (!((y1 >= 0) & (y1 < H))) wy1 = 0.f;

    int px  = min(max(x0, 0), W - 2);
    int x0c = min(max(x0, 0), W - 1);
    int x1c = min(max(x1, 0), W - 1);
    float wA = (x0c == px     ? wx0 : 0.f) + (x1c == px     ? wx1 : 0.f);
    float wB = (x0c == px + 1 ? wx0 : 0.f) + (x1c == px + 1 ? wx1 : 0.f);
    int y0c = min(max(y0, 0), H - 1);
    int y1c = min(max(y1, 0), H - 1);

    s_pidx[wv][h][sub * 2 + 0] = ub + (y0c * 8 + h) * W + px;
    s_w2[wv][h][sub * 2 + 0]   = make_float2(wy0 * wA, wy0 * wB);
    s_pidx[wv][h][sub * 2 + 1] = ub + (y1c * 8 + h) * W + px;
    s_w2[wv][h][sub * 2 + 1]   = make_float2(wy1 * wA, wy1 * wB);
  }
  __syncthreads();

  // --- phase 2: 8-lane cooperative 128B pair gathers ---
  const int colhalf = sub >> 2, e = sub & 3;
  const char* vbb = (const char*)vproj + (size_t)b * 15782400 + sub * 16;

  f32x2 acc0 = {0.f, 0.f}, acc1 = {0.f, 0.f}, acc2 = {0.f, 0.f}, acc3 = {0.f, 0.f};
#pragma unroll
  for (int t = 0; t < 16; ++t) {
    int pidx = s_pidx[wv][h][t];
    float2 w2 = s_w2[wv][h][t];
    float w = colhalf ? w2.y : w2.x;
    uint4 v = *(const uint4*)(vbb + ((size_t)(unsigned)pidx << 6));
    f32x2 wvv = {w, w};
    f32x2 p0 = {__uint_as_float(v.x << 16), __uint_as_float(v.x & 0xffff0000u)};
    f32x2 p1 = {__uint_as_float(v.y << 16), __uint_as_float(v.y & 0xffff0000u)};
    f32x2 p2 = {__uint_as_float(v.z << 16), __uint_as_float(v.z & 0xffff0000u)};
    f32x2 p3 = {__uint_as_float(v.w << 16), __uint_as_float(v.w & 0xffff0000u)};
    acc0 += wvv * p0;
    acc1 += wvv * p1;
    acc2 += wvv * p2;
    acc3 += wvv * p3;
  }

  acc0.x += __shfl_xor(acc0.x, 4);  acc0.y += __shfl_xor(acc0.y, 4);
  acc1.x += __shfl_xor(acc1.x, 4);  acc1.y += __shfl_xor(acc1.y, 4);
  acc2.x += __shfl_xor(acc2.x, 4);  acc2.y += __shfl_xor(acc2.y, 4);
  acc3.x += __shfl_xor(acc3.x, 4);  acc3.y += __shfl_xor(acc3.y, 4);

  if (!colhalf) {
    __half2 h0, h1, h2, h3;
    h0.x = __float2half_rn(acc0.x); h0.y = __float2half_rn(acc0.y);
    h1.x = __float2half_rn(acc1.x); h1.y = __float2half_rn(acc1.y);
    h2.x = __float2half_rn(acc2.x); h2.y = __float2half_rn(acc2.y);
    h3.x = __float2half_rn(acc3.x); h3.y = __float2half_rn(acc3.y);
    uint4 w;
    w.x = *(unsigned*)&h0; w.y = *(unsigned*)&h1;
    w.z = *(unsigned*)&h2; w.w = *(unsigned*)&h3;
    *(uint4*)(partial + (size_t)item * 256 + h * 32 + e * 8) = w;
  }
}

// ---------------------------------------------------------------------------
// Stage B: out[bq][c] = sum_z partial[bq*4+z][c].  Fully streaming.
// ---------------------------------------------------------------------------
__global__ __launch_bounds__(256) void combine_kernel(
    const __half* __restrict__ partial, float* __restrict__ out) {
  int i = blockIdx.x * 256 + threadIdx.x;   // i in [0, 60000*128)
  if (i >= BS * NQ * 128) return;
  int bq = i >> 7, cp = i & 127;
  const __half2* p = (const __half2*)(partial + (size_t)bq * 1024) + cp;
  __half2 a0 = p[0], a1 = p[128], a2 = p[256], a3 = p[384];
  float sx = __half2float(a0.x) + __half2float(a1.x) +
             __half2float(a2.x) + __half2float(a3.x);
  float sy = __half2float(a0.y) + __half2float(a1.y) +
             __half2float(a2.y) + __half2float(a3.y);
  ((float2*)out)[i] = make_float2(sx, sy);
}

extern "C" void kernel_launch(void* const* d_in, const int* in_sizes, int n_in,
                              void* d_out, int out_size, void* d_ws, size_t ws_size,
                              hipStream_t stream) {
  const float* query  = (const float*)d_in[0];
  const float* value  = (const float*)d_in[1];
  const float* refp   = (const float*)d_in[2];
  const float* w_off  = (const float*)d_in[3];
  const float* b_off  = (const float*)d_in[4];
  const float* w_attn = (const float*)d_in[5];
  const float* b_attn = (const float*)d_in[6];
  const float* w_val  = (const float*)d_in[7];
  const float* b_val  = (const float*)d_in[8];
  float* out = (float*)d_out;

  char* ws = (char*)d_ws;
  // layout (bytes):
  //   vproj   bf16 level-blocked  @ 0           (94,694,400)
  //   C2      bf16 [60000*768]    @ 94,694,400  (92,160,000)
  //   wvalT   bf16 [256*256]      @ 186,854,400 (131,072)
  //   wpackT  bf16 [768*256]      @ 186,985,472 (393,216)
  //   bpack   f32  [768]          @ 187,378,688 (3,072)
  //   perm    u32  [240000]       @ 187,381,760 (960,000)
  //   hist    u32  [1536]         @ 188,341,760 (6,144)
  //   partial f16  [240000*256]   @ 188,347,904 (122,880,000) -> end 311,227,904
  unsigned short* vproj  = (unsigned short*)(ws);
  unsigned short* C2     = (unsigned short*)(ws + 94694400);
  unsigned short* wvalT  = (unsigned short*)(ws + 186854400);
  unsigned short* wpackT = (unsigned short*)(ws + 186985472);
  float*          bpack  = (float*)        (ws + 187378688);
  unsigned*       perm   = (unsigned*)     (ws + 187381760);
  unsigned*       hist   = (unsigned*)     (ws + 188341760);
  __half*         partial= (__half*)       (ws + 188347904);

  const int Mv = BS * NV;  // 184950
  const int Mq = BS * NQ;  // 60000
  const int NITEMS = BS * NQ * 4;  // 240000

  hipMemsetAsync(hist, 0, 1536 * 4, stream);

  cell_hist_kernel<<<(NITEMS + 255) / 256, 256, 0, stream>>>(refp, hist);
  scan_kernel<<<1, 256, 0, stream>>>(hist);
  cell_scatter_kernel<<<(NITEMS + 255) / 256, 256, 0, stream>>>(refp, hist, perm);

  prep_weights_kernel<<<1032, 256, 0, stream>>>(w_val, w_off, w_attn, b_off, b_attn,
                                                wvalT, wpackT, bpack);
  gemm_mfma_kernel<true><<<dim3((Mv + 127) / 128, 2), 256, 0, stream>>>(
      value, wvalT, b_val, vproj, Mv, 256);
  gemm_mfma_kernel<false><<<dim3((Mq + 127) / 128, 6), 256, 0, stream>>>(
      query, wpackT, bpack, C2, Mq, 768);

  msda_sample_kernel<<<60000, 256, 0, stream>>>(
      (const __hip_bfloat16*)vproj, (const __hip_bfloat16*)C2, refp, perm, partial);
  combine_kernel<<<(BS * NQ * 128 + 255) / 256, 256, 0, stream>>>(partial, out);
}

// Round 7
// 487.942 us; speedup vs baseline: 4.1169x; 1.0415x over previous
//
#include <hip/hip_runtime.h>
#include <hip/hip_bf16.h>
#include <hip/hip_fp16.h>

#define NQ 10000
#define BS 6
#define NV 30825   // 23200 + 5800 + 1450 + 375

// vproj layout per batch (64B units = one head-row of 32ch bf16):
//   level l: unit = ubase[l] + (y*8 + h)*W + x   (x-adjacent => contiguous)
//   ubase: 0, 185600, 232000, 243600 ; per-batch 246600 units (15,782,400 B)

typedef __attribute__((ext_vector_type(8))) short bf16x8;
typedef __attribute__((ext_vector_type(8))) unsigned short u16x8;
typedef __attribute__((ext_vector_type(4))) float f32x4;
typedef __attribute__((ext_vector_type(2))) float f32x2;

__device__ __forceinline__ void gload_lds16(const void* g, void* l) {
  __builtin_amdgcn_global_load_lds(
      (const __attribute__((address_space(1))) unsigned int*)g,
      (__attribute__((address_space(3))) unsigned int*)l, 16, 0, 0);
}

__device__ __forceinline__ unsigned short bf_bits(float f) {
  __hip_bfloat16 h = __float2bfloat16(f);
  return *(unsigned short*)&h;
}
__device__ __forceinline__ float bfu(unsigned short u) {
  return __uint_as_float((unsigned)u << 16);
}

// ---------------------------------------------------------------------------
// Pack + transpose weights to bf16; also zeroes the sort histogram (runs
// before cell_hist in the stream).
// ---------------------------------------------------------------------------
__global__ __launch_bounds__(256) void prep_weights_kernel(
    const float* __restrict__ w_val, const float* __restrict__ w_off,
    const float* __restrict__ w_attn, const float* __restrict__ b_off,
    const float* __restrict__ b_attn, unsigned short* __restrict__ wvalT,
    unsigned short* __restrict__ wpackT, float* __restrict__ bpack,
    unsigned* __restrict__ hist) {
  int i = blockIdx.x * 256 + threadIdx.x;
  if (i < 65536) {
    int n = i >> 8, k = i & 255;
    wvalT[i] = bf_bits(w_val[k * 256 + n]);
  } else if (i < 65536 + 196608) {
    int j = i - 65536;
    int n = j >> 8, k = j & 255;
    float v = (n < 512) ? w_off[k * 512 + n] : w_attn[k * 256 + (n - 512)];
    wpackT[j] = bf_bits(v);
  } else if (i < 65536 + 196608 + 768) {
    int j = i - 262144;
    bpack[j] = (j < 512) ? b_off[j] : b_attn[j - 512];
  } else if (i >= 263168 && i < 263168 + 1536) {
    hist[i - 263168] = 0u;
  }
}

// ---------------------------------------------------------------------------
// MFMA GEMM, fused A conversion, 2-stage pipeline:
//   C[M,N](bf16) = bf16(A[M,256] f32) @ WT[N,256]^T(bf16) + bias[N](f32)
// 128x128 tile, BK=64, 4 waves. Bs double-buffered (gload_lds); A reg-staged
// with next-tile loads issued BEFORE current-tile compute (latency hidden).
// ---------------------------------------------------------------------------
template <bool SCATTER>
__global__ __launch_bounds__(256) void gemm_mfma_kernel(
    const float* __restrict__ A, const unsigned short* __restrict__ WT,
    const float* __restrict__ bias, unsigned short* __restrict__ C, int M, int N) {
  __shared__ short As[128 * 64];
  __shared__ short Bs[2][128 * 64];
  const int tid = threadIdx.x;
  const int wv = tid >> 6;
  const int lane = tid & 63;
  const int wr = wv >> 1, wc = wv & 1;
  const int m0 = blockIdx.x * 128;
  const int n0 = blockIdx.y * 128;

  f32x4 acc[4][4] = {};
  float4 ar[4][2];

  auto loadA = [&](int kt) {
#pragma unroll
    for (int j = 0; j < 4; ++j) {
      int u = j * 256 + tid;
      int row = u >> 3, oct = u & 7;
      int gr = m0 + row; if (gr >= M) gr = M - 1;
      const float4* ap = (const float4*)(A + (size_t)gr * 256 + kt * 64 + oct * 8);
      ar[j][0] = ap[0]; ar[j][1] = ap[1];
    }
  };
  auto writeA = [&]() {
#pragma unroll
    for (int j = 0; j < 4; ++j) {
      int u = j * 256 + tid;
      int row = u >> 3, oct = u & 7;
      float4 a0 = ar[j][0], a1 = ar[j][1];
      u16x8 pk = { bf_bits(a0.x), bf_bits(a0.y), bf_bits(a0.z), bf_bits(a0.w),
                   bf_bits(a1.x), bf_bits(a1.y), bf_bits(a1.z), bf_bits(a1.w) };
      *(u16x8*)&As[row * 64 + oct * 8] = pk;
    }
  };
  auto stageB = [&](int kt, int buf) {
#pragma unroll
    for (int j = 0; j < 4; ++j) {
      int u = j * 256 + tid;
      int row = u >> 3;
      int kbyte = (u & 7) * 16;
      int ldsoff = (j * 256 + wv * 64) * 16;
      gload_lds16((const char*)WT + (size_t)(n0 + row) * 512 + kt * 128 + kbyte,
                  (char*)Bs[buf] + ldsoff);
    }
  };

  loadA(0);
  stageB(0, 0);
  writeA();
  __syncthreads();

  for (int kt = 0; kt < 4; ++kt) {
    if (kt < 3) { loadA(kt + 1); stageB(kt + 1, (kt + 1) & 1); }
    const short* bs = Bs[kt & 1];
#pragma unroll
    for (int kk = 0; kk < 2; ++kk) {
      bf16x8 af[4], bfr[4];
#pragma unroll
      for (int mi = 0; mi < 4; ++mi) {
        int off = (wr * 64 + mi * 16 + (lane & 15)) * 64 + kk * 32 + (lane >> 4) * 8;
        af[mi] = *(const bf16x8*)&As[off];
      }
#pragma unroll
      for (int ni = 0; ni < 4; ++ni) {
        int off = (wc * 64 + ni * 16 + (lane & 15)) * 64 + kk * 32 + (lane >> 4) * 8;
        bfr[ni] = *(const bf16x8*)&bs[off];
      }
#pragma unroll
      for (int mi = 0; mi < 4; ++mi)
#pragma unroll
        for (int ni = 0; ni < 4; ++ni)
          acc[mi][ni] = __builtin_amdgcn_mfma_f32_16x16x32_bf16(
              af[mi], bfr[ni], acc[mi][ni], 0, 0, 0);
    }
    if (kt < 3) {
      __syncthreads();   // As reads done; drains next-tile Bs gload too
      writeA();
      __syncthreads();   // As(kt+1) visible
    }
  }

  const int colb = n0 + wc * 64 + (lane & 15);
  float bvn[4];
#pragma unroll
  for (int ni = 0; ni < 4; ++ni) bvn[ni] = bias[colb + ni * 16];
#pragma unroll
  for (int mi = 0; mi < 4; ++mi) {
#pragma unroll
    for (int r = 0; r < 4; ++r) {
      int row = m0 + wr * 64 + mi * 16 + (lane >> 4) * 4 + r;
      if (row >= M) continue;
      if (!SCATTER) {
#pragma unroll
        for (int ni = 0; ni < 4; ++ni)
          C[(size_t)row * N + colb + ni * 16] = bf_bits(acc[mi][ni][r] + bvn[ni]);
      } else {
        int b = row / NV;
        int pix = row - b * NV;
        int ubase, Wl, y, x;
        if (pix < 23200)      { int pl = pix;         y = pl / 200; x = pl - y * 200; ubase = 0;      Wl = 200; }
        else if (pix < 29000) { int pl = pix - 23200; y = pl / 100; x = pl - y * 100; ubase = 185600; Wl = 100; }
        else if (pix < 30450) { int pl = pix - 29000; y = pl / 50;  x = pl - y * 50;  ubase = 232000; Wl = 50;  }
        else                  { int pl = pix - 30450; y = pl / 25;  x = pl - y * 25;  ubase = 243600; Wl = 25;  }
        size_t bu = (size_t)b * 246600 + ubase + (size_t)(y * 8) * Wl + x;
#pragma unroll
        for (int ni = 0; ni < 4; ++ni) {
          int col = colb + ni * 16;
          int h = col >> 5, ch = col & 31;
          C[(bu + (size_t)h * Wl) * 32 + ch] = bf_bits(acc[mi][ni][r] + bvn[ni]);
        }
      }
    }
  }
}

// ---------------------------------------------------------------------------
// Spatial counting sort of 240000 (b,q,z) items by (batch, 16x16 Morton cell).
// ---------------------------------------------------------------------------
__device__ __forceinline__ int item_key(const float* ref, int i) {
  int b = i / 40000;
  int rem = i - b * 40000;
  int q = rem >> 2, z = rem & 3;
  float2 rz = *(const float2*)(ref + (size_t)(b * NQ + q) * 8 + z * 2);
  int xq = min(max((int)(rz.x * 16.f), 0), 15);
  int yq = min(max((int)(rz.y * 16.f), 0), 15);
  int m = 0;
#pragma unroll
  for (int j = 0; j < 4; ++j)
    m |= (((xq >> j) & 1) << (2 * j)) | (((yq >> j) & 1) << (2 * j + 1));
  return b * 256 + m;
}

__global__ __launch_bounds__(256) void cell_hist_kernel(
    const float* __restrict__ ref, unsigned* __restrict__ hist) {
  int i = blockIdx.x * 256 + threadIdx.x;
  if (i >= BS * NQ * 4) return;
  atomicAdd(&hist[item_key(ref, i)], 1u);
}

__global__ __launch_bounds__(256) void scan_kernel(unsigned* __restrict__ hist) {
  __shared__ unsigned sdata[256];
  int tid = threadIdx.x;
  unsigned v[6], sum = 0;
#pragma unroll
  for (int j = 0; j < 6; ++j) { v[j] = hist[tid * 6 + j]; sum += v[j]; }
  sdata[tid] = sum;
  __syncthreads();
  for (int d = 1; d < 256; d <<= 1) {
    unsigned t = (tid >= d) ? sdata[tid - d] : 0u;
    __syncthreads();
    sdata[tid] += t;
    __syncthreads();
  }
  unsigned excl = (tid > 0) ? sdata[tid - 1] : 0u;
#pragma unroll
  for (int j = 0; j < 6; ++j) { hist[tid * 6 + j] = excl; excl += v[j]; }
}

__global__ __launch_bounds__(256) void cell_scatter_kernel(
    const float* __restrict__ ref, unsigned* __restrict__ cursor,
    unsigned* __restrict__ perm) {
  int i = blockIdx.x * 256 + threadIdx.x;
  if (i >= BS * NQ * 4) return;
  unsigned pos = atomicAdd(&cursor[item_key(ref, i)], 1u);
  perm[pos] = (unsigned)i;
}

// ---------------------------------------------------------------------------
// Stage A: 4 waves/block, each wave = one sorted (b,q,z) item.
// Fused softmax + bilinear setup -> LDS (weights pre-selected per colhalf);
// 8-lane cooperative 128B pair gathers; per-item 256-channel partial written
// non-atomically as f16.
// ---------------------------------------------------------------------------
__global__ __launch_bounds__(256) void msda_sample_kernel(
    const __hip_bfloat16* __restrict__ vproj,
    const __hip_bfloat16* __restrict__ C2,   // [BS*NQ,768]: 512 off | 256 attn
    const float* __restrict__ ref,
    const unsigned* __restrict__ perm,
    __half* __restrict__ partial) {          // [BS*NQ*4][256] f16
  const int tid = threadIdx.x;
  const int wv = tid >> 6, lane = tid & 63;
  const int sblk = (blockIdx.x & 7) * 7500 + (blockIdx.x >> 3);  // XCD swizzle
  const unsigned item = perm[sblk * 4 + wv];
  const int b = item / 40000;
  const int rem = item - b * 40000;
  const int q = rem >> 2, z = rem & 3;
  const int bq = b * NQ + q;

  __shared__ int   s_pidx[4][8][17];
  __shared__ float s_wsel[4][8][2][17];

  const int h = lane >> 3, sub = lane & 7;
  {
    // --- fused softmax: lane loads 4 logits [h*32 + sub*4 .. +4] ---
    ushort4 lg = *(const ushort4*)((const unsigned short*)C2 +
                                   (size_t)bq * 768 + 512 + lane * 4);
    float l0 = bfu(lg.x), l1 = bfu(lg.y), l2 = bfu(lg.z), l3 = bfu(lg.w);
    float mx = fmaxf(fmaxf(l0, l1), fmaxf(l2, l3));
    mx = fmaxf(mx, __shfl_xor(mx, 1));
    mx = fmaxf(mx, __shfl_xor(mx, 2));
    mx = fmaxf(mx, __shfl_xor(mx, 4));
    float e0 = __expf(l0 - mx), e1 = __expf(l1 - mx),
          e2 = __expf(l2 - mx), e3 = __expf(l3 - mx);
    float sm = e0 + e1 + e2 + e3;
    sm += __shfl_xor(sm, 1);
    sm += __shfl_xor(sm, 2);
    sm += __shfl_xor(sm, 4);
    float ez = (z == 0) ? e0 : (z == 1) ? e1 : (z == 2) ? e2 : e3;
    float aw = ez / sm;

    // --- bilinear setup for sample (h, l, p = z + 4*p2) ---
    const int l = sub >> 1, p2 = sub & 1, p = z + 4 * p2;
    __hip_bfloat162 ob = *(const __hip_bfloat162*)((const unsigned short*)C2 +
        (size_t)bq * 768 + (((h * 4 + l) * 8 + p) << 1));
    float ox = __bfloat162float(ob.x), oy = __bfloat162float(ob.y);
    float2 rz = *(const float2*)(ref + (size_t)bq * 8 + z * 2);

    const int W = (l == 0) ? 200 : (l == 1) ? 100 : (l == 2) ? 50 : 25;
    const int H = (l == 0) ? 116 : (l == 1) ? 58 : (l == 2) ? 29 : 15;
    const int ub = (l == 0) ? 0 : (l == 1) ? 185600 : (l == 2) ? 232000 : 243600;

    float x = rz.x * (float)W + ox - 0.5f;
    float y = rz.y * (float)H + oy - 0.5f;
    float x0f = floorf(x), y0f = floorf(y);
    float lx = x - x0f, ly = y - y0f;
    int x0 = (int)x0f, y0 = (int)y0f;
    int x1 = x0 + 1, y1 = y0 + 1;

    float wx0 = 1.f - lx, wx1 = lx;
    if (!((x0 >= 0) & (x0 < W))) wx0 = 0.f;
    if (!((x1 >= 0) & (x1 < W))) wx1 = 0.f;
    float wy0 = (1.f - ly) * aw, wy1 = ly * aw;
    if (!((y0 >= 0) & (y0 < H))) wy0 = 0.f;
    if (!((y1 >= 0) & (y1 < H))) wy1 = 0.f;

    int px  = min(max(x0, 0), W - 2);
    int x0c = min(max(x0, 0), W - 1);
    int x1c = min(max(x1, 0), W - 1);
    float wA = (x0c == px     ? wx0 : 0.f) + (x1c == px     ? wx1 : 0.f);
    float wB = (x0c == px + 1 ? wx0 : 0.f) + (x1c == px + 1 ? wx1 : 0.f);
    int y0c = min(max(y0, 0), H - 1);
    int y1c = min(max(y1, 0), H - 1);

    const int t0 = sub * 2, t1 = sub * 2 + 1;
    s_pidx[wv][h][t0]     = ub + (y0c * 8 + h) * W + px;
    s_wsel[wv][h][0][t0]  = wy0 * wA;
    s_wsel[wv][h][1][t0]  = wy0 * wB;
    s_pidx[wv][h][t1]     = ub + (y1c * 8 + h) * W + px;
    s_wsel[wv][h][0][t1]  = wy1 * wA;
    s_wsel[wv][h][1][t1]  = wy1 * wB;
  }
  __syncthreads();

  // --- phase 2: 8-lane cooperative 128B pair gathers ---
  const int colhalf = sub >> 2, e = sub & 3;
  const char* vbb = (const char*)vproj + (size_t)b * 15782400 + sub * 16;

  f32x2 acc0 = {0.f, 0.f}, acc1 = {0.f, 0.f}, acc2 = {0.f, 0.f}, acc3 = {0.f, 0.f};
#pragma unroll
  for (int t = 0; t < 16; ++t) {
    int pidx = s_pidx[wv][h][t];
    float w = s_wsel[wv][h][colhalf][t];
    uint4 v = *(const uint4*)(vbb + ((size_t)(unsigned)pidx << 6));
    f32x2 wvv = {w, w};
    f32x2 p0 = {__uint_as_float(v.x << 16), __uint_as_float(v.x & 0xffff0000u)};
    f32x2 p1 = {__uint_as_float(v.y << 16), __uint_as_float(v.y & 0xffff0000u)};
    f32x2 p2 = {__uint_as_float(v.z << 16), __uint_as_float(v.z & 0xffff0000u)};
    f32x2 p3 = {__uint_as_float(v.w << 16), __uint_as_float(v.w & 0xffff0000u)};
    acc0 += wvv * p0;
    acc1 += wvv * p1;
    acc2 += wvv * p2;
    acc3 += wvv * p3;
  }

  acc0.x += __shfl_xor(acc0.x, 4);  acc0.y += __shfl_xor(acc0.y, 4);
  acc1.x += __shfl_xor(acc1.x, 4);  acc1.y += __shfl_xor(acc1.y, 4);
  acc2.x += __shfl_xor(acc2.x, 4);  acc2.y += __shfl_xor(acc2.y, 4);
  acc3.x += __shfl_xor(acc3.x, 4);  acc3.y += __shfl_xor(acc3.y, 4);

  if (!colhalf) {
    __half2 h0, h1, h2, h3;
    h0.x = __float2half_rn(acc0.x); h0.y = __float2half_rn(acc0.y);
    h1.x = __float2half_rn(acc1.x); h1.y = __float2half_rn(acc1.y);
    h2.x = __float2half_rn(acc2.x); h2.y = __float2half_rn(acc2.y);
    h3.x = __float2half_rn(acc3.x); h3.y = __float2half_rn(acc3.y);
    uint4 w;
    w.x = *(unsigned*)&h0; w.y = *(unsigned*)&h1;
    w.z = *(unsigned*)&h2; w.w = *(unsigned*)&h3;
    *(uint4*)(partial + (size_t)item * 256 + h * 32 + e * 8) = w;
  }
}

// ---------------------------------------------------------------------------
// Stage B: out[bq][c] = sum_z partial[bq*4+z][c].  Fully streaming.
// ---------------------------------------------------------------------------
__global__ __launch_bounds__(256) void combine_kernel(
    const __half* __restrict__ partial, float* __restrict__ out) {
  int i = blockIdx.x * 256 + threadIdx.x;   // i in [0, 60000*128)
  if (i >= BS * NQ * 128) return;
  int bq = i >> 7, cp = i & 127;
  const __half2* p = (const __half2*)(partial + (size_t)bq * 1024) + cp;
  __half2 a0 = p[0], a1 = p[128], a2 = p[256], a3 = p[384];
  float sx = __half2float(a0.x) + __half2float(a1.x) +
             __half2float(a2.x) + __half2float(a3.x);
  float sy = __half2float(a0.y) + __half2float(a1.y) +
             __half2float(a2.y) + __half2float(a3.y);
  ((float2*)out)[i] = make_float2(sx, sy);
}

extern "C" void kernel_launch(void* const* d_in, const int* in_sizes, int n_in,
                              void* d_out, int out_size, void* d_ws, size_t ws_size,
                              hipStream_t stream) {
  const float* query  = (const float*)d_in[0];
  const float* value  = (const float*)d_in[1];
  const float* refp   = (const float*)d_in[2];
  const float* w_off  = (const float*)d_in[3];
  const float* b_off  = (const float*)d_in[4];
  const float* w_attn = (const float*)d_in[5];
  const float* b_attn = (const float*)d_in[6];
  const float* w_val  = (const float*)d_in[7];
  const float* b_val  = (const float*)d_in[8];
  float* out = (float*)d_out;

  char* ws = (char*)d_ws;
  // layout (bytes):
  //   vproj   bf16 level-blocked  @ 0           (94,694,400)
  //   C2      bf16 [60000*768]    @ 94,694,400  (92,160,000)
  //   wvalT   bf16 [256*256]      @ 186,854,400 (131,072)
  //   wpackT  bf16 [768*256]      @ 186,985,472 (393,216)
  //   bpack   f32  [768]          @ 187,378,688 (3,072)
  //   perm    u32  [240000]       @ 187,381,760 (960,000)
  //   hist    u32  [1536]         @ 188,341,760 (6,144)
  //   partial f16  [240000*256]   @ 188,347,904 (122,880,000) -> end 311,227,904
  unsigned short* vproj  = (unsigned short*)(ws);
  unsigned short* C2     = (unsigned short*)(ws + 94694400);
  unsigned short* wvalT  = (unsigned short*)(ws + 186854400);
  unsigned short* wpackT = (unsigned short*)(ws + 186985472);
  float*          bpack  = (float*)        (ws + 187378688);
  unsigned*       perm   = (unsigned*)     (ws + 187381760);
  unsigned*       hist   = (unsigned*)     (ws + 188341760);
  __half*         partial= (__half*)       (ws + 188347904);

  const int Mv = BS * NV;  // 184950
  const int Mq = BS * NQ;  // 60000
  const int NITEMS = BS * NQ * 4;  // 240000

  prep_weights_kernel<<<1040, 256, 0, stream>>>(w_val, w_off, w_attn, b_off, b_attn,
                                                wvalT, wpackT, bpack, hist);
  cell_hist_kernel<<<(NITEMS + 255) / 256, 256, 0, stream>>>(refp, hist);
  scan_kernel<<<1, 256, 0, stream>>>(hist);
  cell_scatter_kernel<<<(NITEMS + 255) / 256, 256, 0, stream>>>(refp, hist, perm);

  gemm_mfma_kernel<true><<<dim3((Mv + 127) / 128, 2), 256, 0, stream>>>(
      value, wvalT, b_val, vproj, Mv, 256);
  gemm_mfma_kernel<false><<<dim3((Mq + 127) / 128, 6), 256, 0, stream>>>(
      query, wpackT, bpack, C2, Mq, 768);

  msda_sample_kernel<<<60000, 256, 0, stream>>>(
      (const __hip_bfloat16*)vproj, (const __hip_bfloat16*)C2, refp, perm, partial);
  combine_kernel<<<(BS * NQ * 128 + 255) / 256, 256, 0, stream>>>(partial, out);
}